// Round 4
// baseline (299.270 us; speedup 1.0000x reference)
//
#include <hip/hip_runtime.h>
#include <hip/hip_bf16.h>
#include <stdint.h>

typedef unsigned short u16;
typedef unsigned int   u32;
typedef short bf16x8 __attribute__((ext_vector_type(8)));
typedef float f32x4  __attribute__((ext_vector_type(4)));

// may_alias views for type-punned LDS/global accesses (TBAA-safe)
typedef bf16x8 __attribute__((__may_alias__)) bf16x8_a;
typedef uint4  __attribute__((__may_alias__)) uint4_a;
typedef uint2  __attribute__((__may_alias__)) uint2_a;
typedef float4 __attribute__((__may_alias__)) float4_a;

#define MFMA_BF16(a,b,c) __builtin_amdgcn_mfma_f32_16x16x32_bf16((a),(b),(c),0,0,0)
#define L2E 1.44269504088896340736f

// B=4, S=2048, D=1024, H=16, DH=64
#define SEQ 2048
#define DMODEL 1024
#define NH 16
#define DH 64

__device__ __forceinline__ u32 pack_bf2(float a, float b) {
  union { __hip_bfloat162 h; u32 u; } c;
  c.h = __float22bfloat162_rn(make_float2(a, b));   // v_cvt_pk path on gfx950
  return c.u;
}

__device__ __forceinline__ u16 f2bf(float f) {
  u32 u = __builtin_bit_cast(u32, f);
  u += 0x7FFFu + ((u >> 16) & 1u);
  return (u16)(u >> 16);
}

// global -> LDS direct DMA, 16B/lane. LDS dest is wave-uniform base + lane*16.
__device__ __forceinline__ void gl_lds16(const u16* g, u16* l) {
  __builtin_amdgcn_global_load_lds(
      (const __attribute__((address_space(1))) void*)g,
      (__attribute__((address_space(3))) void*)l, 16, 0, 0);
}

// ---------------------------------------------------------------------------
// One-time f32 -> bf16 converts.
// ---------------------------------------------------------------------------
__global__ __launch_bounds__(256) void cvt_x_bf16(
    const float* __restrict__ s, u16* __restrict__ d, int n8)
{
  int i = blockIdx.x * 256 + threadIdx.x;
  const int stride = gridDim.x * 256;
  for (; i < n8; i += stride) {
    const float4_a* p = (const float4_a*)(s + (size_t)i * 8);
    float4 a = p[0], b = p[1];
    uint4 o;
    o.x = pack_bf2(a.x, a.y); o.y = pack_bf2(a.z, a.w);
    o.z = pack_bf2(b.x, b.y); o.w = pack_bf2(b.z, b.w);
    *(uint4_a*)(d + (size_t)i * 8) = o;
  }
}

// Wq/Wk/Wv in one launch: grid (512, 3), 512*256*8 == 1024*1024 exactly.
__global__ __launch_bounds__(256) void cvt_w_bf16(
    const float* __restrict__ wq, const float* __restrict__ wk, const float* __restrict__ wv,
    u16* __restrict__ oq, u16* __restrict__ ok, u16* __restrict__ ov)
{
  const float* s = (blockIdx.y == 0) ? wq : (blockIdx.y == 1) ? wk : wv;
  u16*         d = (blockIdx.y == 0) ? oq : (blockIdx.y == 1) ? ok : ov;
  const int i = blockIdx.x * 256 + threadIdx.x;
  const float4_a* p = (const float4_a*)(s + (size_t)i * 8);
  float4 a = p[0], b = p[1];
  uint4 o;
  o.x = pack_bf2(a.x, a.y); o.y = pack_bf2(a.z, a.w);
  o.z = pack_bf2(b.x, b.y); o.w = pack_bf2(b.z, b.w);
  *(uint4_a*)(d + (size_t)i * 8) = o;
}

// ---------------------------------------------------------------------------
// QKV projection, bf16 in -> bf16 out (FROZEN from R3 for attribution).
// 128x128 tile, BK=32, dbuf LDS, counted vmcnt(4), raw barriers.
// ---------------------------------------------------------------------------
__global__ __launch_bounds__(256, 4) void qkv_gemm_bf(
    const u16* __restrict__ Xb,
    const u16* __restrict__ Wqb, const u16* __restrict__ Wkb, const u16* __restrict__ Wvb,
    const float* __restrict__ Bq, const float* __restrict__ Bk, const float* __restrict__ Bv,
    u16* __restrict__ Qo, u16* __restrict__ Ko, u16* __restrict__ Vo)
{
  __shared__ u16 As[2][128 * 32];   // [buf][m][k] bf16, row = 64B
  __shared__ u16 Bs[2][128 * 32];   // [buf][n][k] bf16

  const int tid  = threadIdx.x;
  const int lane = tid & 63;
  const int wid  = tid >> 6;
  const int l16  = lane & 15;
  const int quad = lane >> 4;
  const int wm   = (wid >> 1) * 64;
  const int wn   = (wid & 1) * 64;

  const int m0 = blockIdx.x * 128;
  const int n0 = blockIdx.y * 128;
  const int pj = blockIdx.z;

  const u16*   Wb   = (pj == 0) ? Wqb : (pj == 1) ? Wkb : Wvb;
  const float* Bias = (pj == 0) ? Bq : (pj == 1) ? Bk : Bv;
  u16*         Out  = (pj == 0) ? Qo : (pj == 1) ? Ko : Vo;
  const float scale = (pj == 0) ? 0.125f : 1.0f;

  f32x4 acc[4][4];
#pragma unroll
  for (int i = 0; i < 4; i++)
#pragma unroll
    for (int j = 0; j < 4; j++) acc[i][j] = (f32x4){0.f, 0.f, 0.f, 0.f};

  const int lr = lane >> 2;          // row within a 16-row band (4 lanes/row)
  const int lc = (lane & 3) * 8;     // bf16 col offset (8 bf16 = 16B per lane)

  const u16* Arow = Xb + (size_t)m0 * DMODEL;
  const u16* Brow = Wb + (size_t)n0 * DMODEL;

  const int NT = DMODEL / 32;        // 32 K-steps

  // prologue: stage tiles 0,1 into buf 0,1 (8 gl_lds outstanding per wave)
#pragma unroll
  for (int c = 0; c < 2; c++) {
    const int band = c * 64 + wid * 16;
    gl_lds16(Arow + (size_t)(band + lr) * DMODEL + 0 + lc, &As[0][band * 32]);
    gl_lds16(Brow + (size_t)(band + lr) * DMODEL + 0 + lc, &Bs[0][band * 32]);
  }
#pragma unroll
  for (int c = 0; c < 2; c++) {
    const int band = c * 64 + wid * 16;
    gl_lds16(Arow + (size_t)(band + lr) * DMODEL + 32 + lc, &As[1][band * 32]);
    gl_lds16(Brow + (size_t)(band + lr) * DMODEL + 32 + lc, &Bs[1][band * 32]);
  }

  for (int t = 0; t < NT; ++t) {
    const int cur = t & 1;
    // wait for buf[cur]'s 4 loads (oldest); leave newest 4 in flight.
    if (t < NT - 1) asm volatile("s_waitcnt vmcnt(4)" ::: "memory");
    else            asm volatile("s_waitcnt vmcnt(0)" ::: "memory");
    __builtin_amdgcn_s_barrier();          // all waves' buf[cur] landed

    bf16x8 a[4], b[4];
#pragma unroll
    for (int mt = 0; mt < 4; mt++)
      a[mt] = *(const bf16x8_a*)&As[cur][(wm + mt * 16 + l16) * 32 + quad * 8];
#pragma unroll
    for (int nt = 0; nt < 4; nt++)
      b[nt] = *(const bf16x8_a*)&Bs[cur][(wn + nt * 16 + l16) * 32 + quad * 8];

    asm volatile("s_waitcnt lgkmcnt(0)" ::: "memory");  // frags in regs
    __builtin_amdgcn_sched_barrier(0);                  // rule #18
    __builtin_amdgcn_s_barrier();          // all waves done reading buf[cur]

    if (t + 2 < NT) {                      // overwrite buf[cur] with tile t+2
      const int kt2 = (t + 2) * 32;
#pragma unroll
      for (int c = 0; c < 2; c++) {
        const int band = c * 64 + wid * 16;
        gl_lds16(Arow + (size_t)(band + lr) * DMODEL + kt2 + lc, &As[cur][band * 32]);
        gl_lds16(Brow + (size_t)(band + lr) * DMODEL + kt2 + lc, &Bs[cur][band * 32]);
      }
    }

#pragma unroll
    for (int mt = 0; mt < 4; mt++)
#pragma unroll
      for (int nt = 0; nt < 4; nt++)
        acc[mt][nt] = MFMA_BF16(a[mt], b[nt], acc[mt][nt]);
  }

  // Epilogue. C layout: col n = l16(+), row m = quad*4+r(+).
  if (pj == 2) {
    // V stored TRANSPOSED [B,H,DH,S]: per lane 4 consecutive s -> uint2 pack
#pragma unroll
    for (int mt = 0; mt < 4; mt++) {
#pragma unroll
      for (int nt = 0; nt < 4; nt++) {
        const int n = n0 + wn + nt * 16 + l16;
        const float bias = Bias[n];
        const int h = n >> 6, dh = n & 63;
        const int m = m0 + wm + mt * 16 + quad * 4;
        const int bb = m >> 11, ss = m & 2047;
        uint2 pk;
        pk.x = pack_bf2(acc[mt][nt][0] + bias, acc[mt][nt][1] + bias);
        pk.y = pack_bf2(acc[mt][nt][2] + bias, acc[mt][nt][3] + bias);
        *(uint2_a*)&Out[((size_t)(bb * NH + h) * DH + dh) * SEQ + ss] = pk;
      }
    }
  } else {
#pragma unroll
    for (int mt = 0; mt < 4; mt++) {
#pragma unroll
      for (int nt = 0; nt < 4; nt++) {
        const int n = n0 + wn + nt * 16 + l16;
        const float bias = Bias[n];
        const int h = n >> 6, dh = n & 63;
#pragma unroll
        for (int r = 0; r < 4; r++) {
          const int m = m0 + wm + mt * 16 + quad * 4 + r;
          const int bb = m >> 11, ss = m & 2047;
          Out[((((size_t)bb * NH + h) * SEQ + ss) << 6) + dh] = f2bf((acc[mt][nt][r] + bias) * scale);
        }
      }
    }
  }
}

// ---------------------------------------------------------------------------
// QKV projection, f32 in -> bf16 ws (FALLBACK path when ws too small).
// ---------------------------------------------------------------------------
__global__ __launch_bounds__(256, 2) void qkv_gemm(
    const float* __restrict__ X,
    const float* __restrict__ Wq, const float* __restrict__ Wk, const float* __restrict__ Wv,
    const float* __restrict__ Bq, const float* __restrict__ Bk, const float* __restrict__ Bv,
    u16* __restrict__ Qo, u16* __restrict__ Ko, u16* __restrict__ Vo)
{
  __shared__ u16 As[128 * 32];
  __shared__ u16 Bs[128 * 32];

  const int tid  = threadIdx.x;
  const int lane = tid & 63;
  const int wid  = tid >> 6;
  const int l16  = lane & 15;
  const int quad = lane >> 4;
  const int wm   = (wid >> 1) * 64;
  const int wn   = (wid & 1) * 64;

  const int m0 = blockIdx.x * 128;
  const int n0 = blockIdx.y * 128;
  const int pj = blockIdx.z;

  const float* W    = (pj == 0) ? Wq : (pj == 1) ? Wk : Wv;
  const float* Bias = (pj == 0) ? Bq : (pj == 1) ? Bk : Bv;
  u16*         Out  = (pj == 0) ? Qo : (pj == 1) ? Ko : Vo;
  const float scale = (pj == 0) ? 0.125f : 1.0f;

  f32x4 acc[4][4];
#pragma unroll
  for (int i = 0; i < 4; i++)
#pragma unroll
    for (int j = 0; j < 4; j++) acc[i][j] = (f32x4){0.f, 0.f, 0.f, 0.f};

  float4 gX[4], gW[4];
#pragma unroll
  for (int i = 0; i < 4; i++) {
    const int ch = i * 256 + tid;
    const int r = ch >> 3, c = ch & 7;
    gX[i] = *(const float4_a*)(X + (size_t)(m0 + r) * DMODEL + c * 4);
    gW[i] = *(const float4_a*)(W + (size_t)(n0 + r) * DMODEL + c * 4);
  }

  for (int kt = 0; kt < DMODEL; kt += 32) {
    __syncthreads();
#pragma unroll
    for (int i = 0; i < 4; i++) {
      const int ch = i * 256 + tid;
      const int r = ch >> 3, c = ch & 7;
      uint2 xp, wp;
      xp.x = pack_bf2(gX[i].x, gX[i].y);  xp.y = pack_bf2(gX[i].z, gX[i].w);
      wp.x = pack_bf2(gW[i].x, gW[i].y);  wp.y = pack_bf2(gW[i].z, gW[i].w);
      *(uint2_a*)&As[r * 32 + c * 4] = xp;
      *(uint2_a*)&Bs[r * 32 + c * 4] = wp;
    }
    __syncthreads();

    if (kt + 32 < DMODEL) {
#pragma unroll
      for (int i = 0; i < 4; i++) {
        const int ch = i * 256 + tid;
        const int r = ch >> 3, c = ch & 7;
        gX[i] = *(const float4_a*)(X + (size_t)(m0 + r) * DMODEL + kt + 32 + c * 4);
        gW[i] = *(const float4_a*)(W + (size_t)(n0 + r) * DMODEL + kt + 32 + c * 4);
      }
    }

    bf16x8 a[4], b[4];
#pragma unroll
    for (int mt = 0; mt < 4; mt++)
      a[mt] = *(const bf16x8_a*)&As[(wm + mt * 16 + l16) * 32 + quad * 8];
#pragma unroll
    for (int nt = 0; nt < 4; nt++)
      b[nt] = *(const bf16x8_a*)&Bs[(wn + nt * 16 + l16) * 32 + quad * 8];
#pragma unroll
    for (int mt = 0; mt < 4; mt++)
#pragma unroll
      for (int nt = 0; nt < 4; nt++)
        acc[mt][nt] = MFMA_BF16(a[mt], b[nt], acc[mt][nt]);
  }

  if (pj == 2) {
#pragma unroll
    for (int mt = 0; mt < 4; mt++) {
#pragma unroll
      for (int nt = 0; nt < 4; nt++) {
        const int n = n0 + wn + nt * 16 + l16;
        const float bias = Bias[n];
        const int h = n >> 6, dh = n & 63;
        const int m = m0 + wm + mt * 16 + quad * 4;
        const int bb = m >> 11, ss = m & 2047;
        uint2 pk;
        pk.x = pack_bf2(acc[mt][nt][0] + bias, acc[mt][nt][1] + bias);
        pk.y = pack_bf2(acc[mt][nt][2] + bias, acc[mt][nt][3] + bias);
        *(uint2_a*)&Out[((size_t)(bb * NH + h) * DH + dh) * SEQ + ss] = pk;
      }
    }
  } else {
#pragma unroll
    for (int mt = 0; mt < 4; mt++) {
#pragma unroll
      for (int nt = 0; nt < 4; nt++) {
        const int n = n0 + wn + nt * 16 + l16;
        const float bias = Bias[n];
        const int h = n >> 6, dh = n & 63;
#pragma unroll
        for (int r = 0; r < 4; r++) {
          const int m = m0 + wm + mt * 16 + quad * 4 + r;
          const int bb = m >> 11, ss = m & 2047;
          Out[((((size_t)bb * NH + h) * SEQ + ss) << 6) + dh] = f2bf((acc[mt][nt][r] + bias) * scale);
        }
      }
    }
  }
}

// ---------------------------------------------------------------------------
// Causal flash attention -- INDEPENDENT 1-WAVE BLOCKS (this round's rework).
// Grid 4096 = 64 bh x 64 q-tiles of 32 rows. Zero barriers; K/V/Q fragments
// loaded straight from global (L2-resident; bh pinned to one XCD via idx%8
// swizzle so 8 bh x 512KB = 4MB fills that XCD's L2). P goes through a
// 4.6KB wave-private LDS slice (same-wave lgkmcnt ordering only).
// Latency hiding = many independent waves/SIMD instead of lockstep chain.
// Q,K [B*H][S][DH]; V TRANSPOSED [B*H][DH][S]. Q pre-scaled 1/8.
// ---------------------------------------------------------------------------
__global__ __launch_bounds__(64, 4) void flash_attn(
    const u16* __restrict__ Q, const u16* __restrict__ K, const u16* __restrict__ VT,
    float* __restrict__ O)
{
  __shared__ u16 Ps[32 * 72];            // [32 q][72 kv] bf16, 4.6 KB

  const int lane = threadIdx.x & 63;
  const int l16  = lane & 15;
  const int quad = lane >> 4;

  // idx -> (bh, t): all blocks of a bh land on one XCD (idx%8 = bh%8);
  // long tiles (large t) dispatched first.
  const int idx = blockIdx.x;            // 0..4095
  const int hi  = idx >> 3;              // 0..511
  const int t   = 63 - (hi >> 3);        // q-tile, 32 rows
  const int bh  = ((hi & 7) << 3) | (idx & 7);
  const int bb  = bh >> 4, hh = bh & 15;
  const int qbase = t * 32;

  const u16* Qh = Q  + (size_t)bh * (SEQ * DH);
  const u16* Kh = K  + (size_t)bh * (SEQ * DH);
  const u16* Vh = VT + (size_t)bh * (DH * SEQ);

  // Q fragments straight from global: B[n=q][k=dh], 16B/lane contiguous.
  bf16x8 qf[2][2];
#pragma unroll
  for (int ct = 0; ct < 2; ct++)
#pragma unroll
    for (int ks = 0; ks < 2; ks++)
      qf[ct][ks] = *(const bf16x8_a*)(Qh + (size_t)(qbase + ct * 16 + l16) * DH + ks * 32 + quad * 8);

  f32x4 o[4][2];                         // O^T [dt][ct]: row dh=quad*4+r, col q=l16
#pragma unroll
  for (int dt = 0; dt < 4; dt++)
#pragma unroll
    for (int ct = 0; ct < 2; ct++) o[dt][ct] = (f32x4){0.f, 0.f, 0.f, 0.f};

  float mold[2] = {-1e30f, -1e30f};
  float lsum[2] = {0.f, 0.f};

  const int nj = (t >> 1) + 1;           // kv tiles of 64 covering [0, qbase+32)

  for (int j = 0; j < nj; j++) {
    const int kb = j * 64;

    // K fragments straight from global: A[kv][dh], 16B/lane contiguous.
    bf16x8 ka[4][2];
#pragma unroll
    for (int rt = 0; rt < 4; rt++)
#pragma unroll
      for (int ks = 0; ks < 2; ks++)
        ka[rt][ks] = *(const bf16x8_a*)(Kh + (size_t)(kb + rt * 16 + l16) * DH + ks * 32 + quad * 8);

    // S^T = K Q^T: rows kv (4x16), cols q (2x16)
    f32x4 s[4][2];
#pragma unroll
    for (int rt = 0; rt < 4; rt++)
#pragma unroll
      for (int ct = 0; ct < 2; ct++) {
        f32x4 c = (f32x4){0.f, 0.f, 0.f, 0.f};
        c = MFMA_BF16(ka[rt][0], qf[ct][0], c);
        c = MFMA_BF16(ka[rt][1], qf[ct][1], c);
        s[rt][ct] = c;
      }

    if (j == nj - 1) {                   // causal mask on the last tile
#pragma unroll
      for (int rt = 0; rt < 4; rt++)
#pragma unroll
        for (int ct = 0; ct < 2; ct++) {
          const int ql = qbase + ct * 16 + l16;
#pragma unroll
          for (int r = 0; r < 4; r++) {
            const int kvg = kb + rt * 16 + quad * 4 + r;
            if (kvg > ql) s[rt][ct][r] = -1e30f;
          }
        }
    }

    // online softmax per q col (state at l16, replicated across quads).
#pragma unroll
    for (int ct = 0; ct < 2; ct++) {
      float m0_ = fmaxf(fmaxf(s[0][ct][0], s[0][ct][1]), fmaxf(s[0][ct][2], s[0][ct][3]));
      float m1_ = fmaxf(fmaxf(s[1][ct][0], s[1][ct][1]), fmaxf(s[1][ct][2], s[1][ct][3]));
      float m2_ = fmaxf(fmaxf(s[2][ct][0], s[2][ct][1]), fmaxf(s[2][ct][2], s[2][ct][3]));
      float m3_ = fmaxf(fmaxf(s[3][ct][0], s[3][ct][1]), fmaxf(s[3][ct][2], s[3][ct][3]));
      float mt = fmaxf(fmaxf(m0_, m1_), fmaxf(m2_, m3_));
      mt = fmaxf(mt, __shfl_xor(mt, 16));
      mt = fmaxf(mt, __shfl_xor(mt, 32));

      // T13 defer-rescale: only rescale when some column's max grew by > 8
      if (!__all(mt - mold[ct] <= 8.0f)) {
        const float mnew = fmaxf(mold[ct], mt);
        const float a = __builtin_amdgcn_exp2f((mold[ct] - mnew) * L2E);
        lsum[ct] *= a;
        mold[ct] = mnew;
#pragma unroll
        for (int dt = 0; dt < 4; dt++)
#pragma unroll
          for (int r = 0; r < 4; r++) o[dt][ct][r] *= a;
      }
      const float mref = mold[ct];

#pragma unroll
      for (int rt = 0; rt < 4; rt++)
#pragma unroll
        for (int r = 0; r < 4; r++)
          s[rt][ct][r] = __builtin_amdgcn_exp2f((s[rt][ct][r] - mref) * L2E);

      float t0 = (s[0][ct][0] + s[0][ct][1]) + (s[0][ct][2] + s[0][ct][3]);
      float t1 = (s[1][ct][0] + s[1][ct][1]) + (s[1][ct][2] + s[1][ct][3]);
      float t2 = (s[2][ct][0] + s[2][ct][1]) + (s[2][ct][2] + s[2][ct][3]);
      float t3 = (s[3][ct][0] + s[3][ct][1]) + (s[3][ct][2] + s[3][ct][3]);
      float ls = (t0 + t1) + (t2 + t3);
      ls += __shfl_xor(ls, 16);
      ls += __shfl_xor(ls, 32);
      lsum[ct] += ls;
    }

    // P^T -> wave-private LDS: per (rt,ct) 4 consecutive kv -> uint2
#pragma unroll
    for (int rt = 0; rt < 4; rt++)
#pragma unroll
      for (int ct = 0; ct < 2; ct++) {
        uint2 pk;
        pk.x = pack_bf2(s[rt][ct][0], s[rt][ct][1]);
        pk.y = pack_bf2(s[rt][ct][2], s[rt][ct][3]);
        *(uint2_a*)&Ps[(ct * 16 + l16) * 72 + rt * 16 + quad * 4] = pk;
      }

    // V fragments straight from global (issued before the lgkm wait so they
    // fly under it): A[dh][kv], 16B/lane contiguous.
    bf16x8 vt[4][2];
#pragma unroll
    for (int ks2 = 0; ks2 < 2; ks2++)
#pragma unroll
      for (int dt = 0; dt < 4; dt++)
        vt[dt][ks2] = *(const bf16x8_a*)(Vh + (size_t)(dt * 16 + l16) * SEQ + kb + ks2 * 32 + quad * 8);

    // same-wave write->read ordering only (no barrier)
    asm volatile("s_waitcnt lgkmcnt(0)" ::: "memory");
    __builtin_amdgcn_sched_barrier(0);   // rule #18

    // O^T += V^T P^T
#pragma unroll
    for (int ks2 = 0; ks2 < 2; ks2++) {
      bf16x8 pb[2];
#pragma unroll
      for (int ct = 0; ct < 2; ct++)
        pb[ct] = *(const bf16x8_a*)&Ps[(ct * 16 + l16) * 72 + ks2 * 32 + quad * 8];
#pragma unroll
      for (int dt = 0; dt < 4; dt++)
#pragma unroll
        for (int ct = 0; ct < 2; ct++)
          o[dt][ct] = MFMA_BF16(vt[dt][ks2], pb[ct], o[dt][ct]);
    }
  }

  // epilogue: O^T row dh = dt*16+quad*4+r, col q = l16 -> float4 stores
#pragma unroll
  for (int ct = 0; ct < 2; ct++) {
    const float inv = 1.0f / lsum[ct];
    const int qg = qbase + ct * 16 + l16;
    float* orow = O + (size_t)((size_t)bb * SEQ + qg) * DMODEL + hh * 64;
#pragma unroll
    for (int dt = 0; dt < 4; dt++) {
      float4 v4;
      v4.x = o[dt][ct][0] * inv;  v4.y = o[dt][ct][1] * inv;
      v4.z = o[dt][ct][2] * inv;  v4.w = o[dt][ct][3] * inv;
      *(float4_a*)&orow[dt * 16 + quad * 4] = v4;
    }
  }
}

// Distinctive-paint sentinel (host-decided, graph-safe)
__global__ void paintf(float* out, int n, float v) {
  int i = blockIdx.x * 256 + threadIdx.x;
  if (i < n) out[i] = v;
}

extern "C" void kernel_launch(void* const* d_in, const int* in_sizes, int n_in,
                              void* d_out, int out_size, void* d_ws, size_t ws_size,
                              hipStream_t stream) {
  float* out = (float*)d_out;

  const size_t elems  = (size_t)4 * SEQ * DMODEL;   // 8,388,608 per tensor
  const size_t welems = (size_t)DMODEL * DMODEL;    // 1,048,576 per W
  const size_t need_old = 3 * elems * sizeof(u16);
  const size_t need_new = (4 * elems + 3 * welems) * sizeof(u16);  // ~70 MB

  if (ws_size < need_old) {
    paintf<<<(out_size + 255) / 256, 256, 0, stream>>>(out, out_size, 3.0e38f);
    return;
  }

  const float* x  = (const float*)d_in[0];
  // d_in[1] = mask (causal, unused — structure is known)
  const float* Wq = (const float*)d_in[2];
  const float* bq = (const float*)d_in[3];
  const float* Wk = (const float*)d_in[4];
  const float* bk = (const float*)d_in[5];
  const float* Wv = (const float*)d_in[6];
  const float* bv = (const float*)d_in[7];

  u16* q = (u16*)d_ws;
  u16* k = q + elems;
  u16* v = k + elems;   // holds V^T [B,H,DH,S]

  if (ws_size >= need_new) {
    u16* xb  = v + elems;
    u16* wqb = xb + elems;
    u16* wkb = wqb + welems;
    u16* wvb = wkb + welems;
    cvt_x_bf16<<<2048, 256, 0, stream>>>(x, xb, (int)(elems / 8));
    cvt_w_bf16<<<dim3(512, 3), 256, 0, stream>>>(Wq, Wk, Wv, wqb, wkb, wvb);
    qkv_gemm_bf<<<dim3(64, 8, 3), 256, 0, stream>>>(xb, wqb, wkb, wvb, bq, bk, bv, q, k, v);
  } else {
    qkv_gemm<<<dim3(64, 8, 3), 256, 0, stream>>>(x, Wq, Wk, Wv, bq, bk, bv, q, k, v);
  }

  flash_attn<<<4096, 64, 0, stream>>>(q, k, v, out);
}

// Round 5
// 270.609 us; speedup vs baseline: 1.1059x; 1.1059x over previous
//
#include <hip/hip_runtime.h>
#include <hip/hip_bf16.h>
#include <stdint.h>

typedef unsigned short u16;
typedef unsigned int   u32;
typedef short bf16x8 __attribute__((ext_vector_type(8)));
typedef float f32x4  __attribute__((ext_vector_type(4)));

// may_alias views for type-punned LDS/global accesses (TBAA-safe)
typedef bf16x8 __attribute__((__may_alias__)) bf16x8_a;
typedef uint4  __attribute__((__may_alias__)) uint4_a;
typedef uint2  __attribute__((__may_alias__)) uint2_a;
typedef float4 __attribute__((__may_alias__)) float4_a;

#define MFMA_BF16(a,b,c) __builtin_amdgcn_mfma_f32_16x16x32_bf16((a),(b),(c),0,0,0)
#define L2E 1.44269504088896340736f

// B=4, S=2048, D=1024, H=16, DH=64
#define SEQ 2048
#define DMODEL 1024
#define NH 16
#define DH 64

__device__ __forceinline__ u32 pack_bf2(float a, float b) {
  union { __hip_bfloat162 h; u32 u; } c;
  c.h = __float22bfloat162_rn(make_float2(a, b));   // v_cvt_pk path on gfx950
  return c.u;
}

__device__ __forceinline__ u16 f2bf(float f) {
  u32 u = __builtin_bit_cast(u32, f);
  u += 0x7FFFu + ((u >> 16) & 1u);
  return (u16)(u >> 16);
}

// global -> LDS direct DMA, 16B/lane. LDS dest is wave-uniform base + lane*16.
__device__ __forceinline__ void gl_lds16(const u16* g, u16* l) {
  __builtin_amdgcn_global_load_lds(
      (const __attribute__((address_space(1))) void*)g,
      (__attribute__((address_space(3))) void*)l, 16, 0, 0);
}

// ---------------------------------------------------------------------------
// One-time f32 -> bf16 converts.
// ---------------------------------------------------------------------------
__global__ __launch_bounds__(256) void cvt_x_bf16(
    const float* __restrict__ s, u16* __restrict__ d, int n8)
{
  int i = blockIdx.x * 256 + threadIdx.x;
  const int stride = gridDim.x * 256;
  for (; i < n8; i += stride) {
    const float4_a* p = (const float4_a*)(s + (size_t)i * 8);
    float4 a = p[0], b = p[1];
    uint4 o;
    o.x = pack_bf2(a.x, a.y); o.y = pack_bf2(a.z, a.w);
    o.z = pack_bf2(b.x, b.y); o.w = pack_bf2(b.z, b.w);
    *(uint4_a*)(d + (size_t)i * 8) = o;
  }
}

// Wq/Wk/Wv in one launch: grid (512, 3), 512*256*8 == 1024*1024 exactly.
__global__ __launch_bounds__(256) void cvt_w_bf16(
    const float* __restrict__ wq, const float* __restrict__ wk, const float* __restrict__ wv,
    u16* __restrict__ oq, u16* __restrict__ ok, u16* __restrict__ ov)
{
  const float* s = (blockIdx.y == 0) ? wq : (blockIdx.y == 1) ? wk : wv;
  u16*         d = (blockIdx.y == 0) ? oq : (blockIdx.y == 1) ? ok : ov;
  const int i = blockIdx.x * 256 + threadIdx.x;
  const float4_a* p = (const float4_a*)(s + (size_t)i * 8);
  float4 a = p[0], b = p[1];
  uint4 o;
  o.x = pack_bf2(a.x, a.y); o.y = pack_bf2(a.z, a.w);
  o.z = pack_bf2(b.x, b.y); o.w = pack_bf2(b.z, b.w);
  *(uint4_a*)(d + (size_t)i * 8) = o;
}

// ---------------------------------------------------------------------------
// QKV projection, bf16 in -> bf16 out. 128x128 tile, BK=32, dbuf LDS,
// counted vmcnt(4), raw barriers (R3 machinery). THIS ROUND: grid (64,4,3)
// = 768 blocks = exactly 3 blocks/CU in ONE residency round (was 1536 at
// 4/CU -> 4+2 ragged rounds, >=33% tail waste). Each block computes 2
// sequential 128-wide n-subtiles; A panel is L2-warm on the second.
// y = x @ W^T + b.  Q: [B,H,S,DH] scaled 0.125. K: [B,H,S,DH]. V: [B,H,DH,S].
// ---------------------------------------------------------------------------
__global__ __launch_bounds__(256, 3) void qkv_gemm_bf(
    const u16* __restrict__ Xb,
    const u16* __restrict__ Wqb, const u16* __restrict__ Wkb, const u16* __restrict__ Wvb,
    const float* __restrict__ Bq, const float* __restrict__ Bk, const float* __restrict__ Bv,
    u16* __restrict__ Qo, u16* __restrict__ Ko, u16* __restrict__ Vo)
{
  __shared__ u16 As[2][128 * 32];   // [buf][m][k] bf16, row = 64B
  __shared__ u16 Bs[2][128 * 32];   // [buf][n][k] bf16

  const int tid  = threadIdx.x;
  const int lane = tid & 63;
  const int wid  = tid >> 6;
  const int l16  = lane & 15;
  const int quad = lane >> 4;
  const int wm   = (wid >> 1) * 64;
  const int wn   = (wid & 1) * 64;

  const int m0 = blockIdx.x * 128;
  const int pj = blockIdx.z;

  const u16*   Wb   = (pj == 0) ? Wqb : (pj == 1) ? Wkb : Wvb;
  const float* Bias = (pj == 0) ? Bq : (pj == 1) ? Bk : Bv;
  u16*         Out  = (pj == 0) ? Qo : (pj == 1) ? Ko : Vo;
  const float scale = (pj == 0) ? 0.125f : 1.0f;

  const int lr = lane >> 2;          // row within a 16-row band (4 lanes/row)
  const int lc = (lane & 3) * 8;     // bf16 col offset (8 bf16 = 16B per lane)

  const u16* Arow = Xb + (size_t)m0 * DMODEL;
  const int NT = DMODEL / 32;        // 32 K-steps

  for (int nsub = 0; nsub < 2; ++nsub) {
    const int n0 = blockIdx.y * 256 + nsub * 128;
    const u16* Brow = Wb + (size_t)n0 * DMODEL;

    f32x4 acc[4][4];
#pragma unroll
    for (int i = 0; i < 4; i++)
#pragma unroll
      for (int j = 0; j < 4; j++) acc[i][j] = (f32x4){0.f, 0.f, 0.f, 0.f};

    // prologue: stage tiles 0,1 into buf 0,1 (8 gl_lds outstanding per wave)
#pragma unroll
    for (int c = 0; c < 2; c++) {
      const int band = c * 64 + wid * 16;
      gl_lds16(Arow + (size_t)(band + lr) * DMODEL + 0 + lc, &As[0][band * 32]);
      gl_lds16(Brow + (size_t)(band + lr) * DMODEL + 0 + lc, &Bs[0][band * 32]);
    }
#pragma unroll
    for (int c = 0; c < 2; c++) {
      const int band = c * 64 + wid * 16;
      gl_lds16(Arow + (size_t)(band + lr) * DMODEL + 32 + lc, &As[1][band * 32]);
      gl_lds16(Brow + (size_t)(band + lr) * DMODEL + 32 + lc, &Bs[1][band * 32]);
    }

    for (int t = 0; t < NT; ++t) {
      const int cur = t & 1;
      // wait for buf[cur]'s 4 loads (oldest); leave newest 4 in flight.
      if (t < NT - 1) asm volatile("s_waitcnt vmcnt(4)" ::: "memory");
      else            asm volatile("s_waitcnt vmcnt(0)" ::: "memory");
      __builtin_amdgcn_s_barrier();          // all waves' buf[cur] landed

      bf16x8 a[4], b[4];
#pragma unroll
      for (int mt = 0; mt < 4; mt++)
        a[mt] = *(const bf16x8_a*)&As[cur][(wm + mt * 16 + l16) * 32 + quad * 8];
#pragma unroll
      for (int nt = 0; nt < 4; nt++)
        b[nt] = *(const bf16x8_a*)&Bs[cur][(wn + nt * 16 + l16) * 32 + quad * 8];

      asm volatile("s_waitcnt lgkmcnt(0)" ::: "memory");  // frags in regs
      __builtin_amdgcn_sched_barrier(0);                  // rule #18
      __builtin_amdgcn_s_barrier();          // all waves done reading buf[cur]

      if (t + 2 < NT) {                      // overwrite buf[cur] with tile t+2
        const int kt2 = (t + 2) * 32;
#pragma unroll
        for (int c = 0; c < 2; c++) {
          const int band = c * 64 + wid * 16;
          gl_lds16(Arow + (size_t)(band + lr) * DMODEL + kt2 + lc, &As[cur][band * 32]);
          gl_lds16(Brow + (size_t)(band + lr) * DMODEL + kt2 + lc, &Bs[cur][band * 32]);
        }
      }

#pragma unroll
      for (int mt = 0; mt < 4; mt++)
#pragma unroll
        for (int nt = 0; nt < 4; nt++)
          acc[mt][nt] = MFMA_BF16(a[mt], b[nt], acc[mt][nt]);
    }

    // Epilogue. C layout: col n = l16(+), row m = quad*4+r(+).
    if (pj == 2) {
      // V stored TRANSPOSED [B,H,DH,S]: per lane 4 consecutive s -> uint2 pack
#pragma unroll
      for (int mt = 0; mt < 4; mt++) {
#pragma unroll
        for (int nt = 0; nt < 4; nt++) {
          const int n = n0 + wn + nt * 16 + l16;
          const float bias = Bias[n];
          const int h = n >> 6, dh = n & 63;
          const int m = m0 + wm + mt * 16 + quad * 4;
          const int bb = m >> 11, ss = m & 2047;
          uint2 pk;
          pk.x = pack_bf2(acc[mt][nt][0] + bias, acc[mt][nt][1] + bias);
          pk.y = pack_bf2(acc[mt][nt][2] + bias, acc[mt][nt][3] + bias);
          *(uint2_a*)&Out[((size_t)(bb * NH + h) * DH + dh) * SEQ + ss] = pk;
        }
      }
    } else {
#pragma unroll
      for (int mt = 0; mt < 4; mt++) {
#pragma unroll
        for (int nt = 0; nt < 4; nt++) {
          const int n = n0 + wn + nt * 16 + l16;
          const float bias = Bias[n];
          const int h = n >> 6, dh = n & 63;
#pragma unroll
          for (int r = 0; r < 4; r++) {
            const int m = m0 + wm + mt * 16 + quad * 4 + r;
            const int bb = m >> 11, ss = m & 2047;
            Out[((((size_t)bb * NH + h) * SEQ + ss) << 6) + dh] = f2bf((acc[mt][nt][r] + bias) * scale);
          }
        }
      }
    }

    if (nsub == 0) {
      // drain epilogue stores so the next subtile's vmcnt(4) count is clean
      asm volatile("s_waitcnt vmcnt(0)" ::: "memory");
    }
  }
}

// ---------------------------------------------------------------------------
// QKV projection, f32 in -> bf16 ws (FALLBACK path when ws too small).
// ---------------------------------------------------------------------------
__global__ __launch_bounds__(256, 2) void qkv_gemm(
    const float* __restrict__ X,
    const float* __restrict__ Wq, const float* __restrict__ Wk, const float* __restrict__ Wv,
    const float* __restrict__ Bq, const float* __restrict__ Bk, const float* __restrict__ Bv,
    u16* __restrict__ Qo, u16* __restrict__ Ko, u16* __restrict__ Vo)
{
  __shared__ u16 As[128 * 32];
  __shared__ u16 Bs[128 * 32];

  const int tid  = threadIdx.x;
  const int lane = tid & 63;
  const int wid  = tid >> 6;
  const int l16  = lane & 15;
  const int quad = lane >> 4;
  const int wm   = (wid >> 1) * 64;
  const int wn   = (wid & 1) * 64;

  const int m0 = blockIdx.x * 128;
  const int n0 = blockIdx.y * 128;
  const int pj = blockIdx.z;

  const float* W    = (pj == 0) ? Wq : (pj == 1) ? Wk : Wv;
  const float* Bias = (pj == 0) ? Bq : (pj == 1) ? Bk : Bv;
  u16*         Out  = (pj == 0) ? Qo : (pj == 1) ? Ko : Vo;
  const float scale = (pj == 0) ? 0.125f : 1.0f;

  f32x4 acc[4][4];
#pragma unroll
  for (int i = 0; i < 4; i++)
#pragma unroll
    for (int j = 0; j < 4; j++) acc[i][j] = (f32x4){0.f, 0.f, 0.f, 0.f};

  float4 gX[4], gW[4];
#pragma unroll
  for (int i = 0; i < 4; i++) {
    const int ch = i * 256 + tid;
    const int r = ch >> 3, c = ch & 7;
    gX[i] = *(const float4_a*)(X + (size_t)(m0 + r) * DMODEL + c * 4);
    gW[i] = *(const float4_a*)(W + (size_t)(n0 + r) * DMODEL + c * 4);
  }

  for (int kt = 0; kt < DMODEL; kt += 32) {
    __syncthreads();
#pragma unroll
    for (int i = 0; i < 4; i++) {
      const int ch = i * 256 + tid;
      const int r = ch >> 3, c = ch & 7;
      uint2 xp, wp;
      xp.x = pack_bf2(gX[i].x, gX[i].y);  xp.y = pack_bf2(gX[i].z, gX[i].w);
      wp.x = pack_bf2(gW[i].x, gW[i].y);  wp.y = pack_bf2(gW[i].z, gW[i].w);
      *(uint2_a*)&As[r * 32 + c * 4] = xp;
      *(uint2_a*)&Bs[r * 32 + c * 4] = wp;
    }
    __syncthreads();

    if (kt + 32 < DMODEL) {
#pragma unroll
      for (int i = 0; i < 4; i++) {
        const int ch = i * 256 + tid;
        const int r = ch >> 3, c = ch & 7;
        gX[i] = *(const float4_a*)(X + (size_t)(m0 + r) * DMODEL + kt + 32 + c * 4);
        gW[i] = *(const float4_a*)(W + (size_t)(n0 + r) * DMODEL + kt + 32 + c * 4);
      }
    }

    bf16x8 a[4], b[4];
#pragma unroll
    for (int mt = 0; mt < 4; mt++)
      a[mt] = *(const bf16x8_a*)&As[(wm + mt * 16 + l16) * 32 + quad * 8];
#pragma unroll
    for (int nt = 0; nt < 4; nt++)
      b[nt] = *(const bf16x8_a*)&Bs[(wn + nt * 16 + l16) * 32 + quad * 8];
#pragma unroll
    for (int mt = 0; mt < 4; mt++)
#pragma unroll
      for (int nt = 0; nt < 4; nt++)
        acc[mt][nt] = MFMA_BF16(a[mt], b[nt], acc[mt][nt]);
  }

  if (pj == 2) {
#pragma unroll
    for (int mt = 0; mt < 4; mt++) {
#pragma unroll
      for (int nt = 0; nt < 4; nt++) {
        const int n = n0 + wn + nt * 16 + l16;
        const float bias = Bias[n];
        const int h = n >> 6, dh = n & 63;
        const int m = m0 + wm + mt * 16 + quad * 4;
        const int bb = m >> 11, ss = m & 2047;
        uint2 pk;
        pk.x = pack_bf2(acc[mt][nt][0] + bias, acc[mt][nt][1] + bias);
        pk.y = pack_bf2(acc[mt][nt][2] + bias, acc[mt][nt][3] + bias);
        *(uint2_a*)&Out[((size_t)(bb * NH + h) * DH + dh) * SEQ + ss] = pk;
      }
    }
  } else {
#pragma unroll
    for (int mt = 0; mt < 4; mt++) {
#pragma unroll
      for (int nt = 0; nt < 4; nt++) {
        const int n = n0 + wn + nt * 16 + l16;
        const float bias = Bias[n];
        const int h = n >> 6, dh = n & 63;
#pragma unroll
        for (int r = 0; r < 4; r++) {
          const int m = m0 + wm + mt * 16 + quad * 4 + r;
          const int bb = m >> 11, ss = m & 2047;
          Out[((((size_t)bb * NH + h) * SEQ + ss) << 6) + dh] = f2bf((acc[mt][nt][r] + bias) * scale);
        }
      }
    }
  }
}

// ---------------------------------------------------------------------------
// Causal flash attention, KVBLK=64, 4 blocks/CU (36KB LDS) -- R2 structure
// (LDS-staged K/V shared by 4 waves = L2-friendly; R4's per-wave global
// reads were L2-BW-bound). THIS ROUND: shuffle-free softmax common path --
// (1) per-lane tree max + __all defer check (T13): no cross-lane reduce
// unless the running max grows by >8 (rare); (2) row-sum of P computed on
// the MATRIX pipe via an all-ones A-fragment (lacc = MFMA(ones, P, lacc)),
// removing the 2 serial shuffle-adds. Common path has ZERO cross-lane ops.
// Q,K [B*H][S][DH]; V TRANSPOSED [B*H][DH][S]. Q pre-scaled 1/8.
// ---------------------------------------------------------------------------
__global__ __launch_bounds__(256, 4) void flash_attn(
    const u16* __restrict__ Q, const u16* __restrict__ K, const u16* __restrict__ VT,
    float* __restrict__ O)
{
  __shared__ u16 Ks[64 * 72];          // [kv][72]   9 KB
  __shared__ u16 VTs[64 * 72];         // [dh][72]   9 KB
  __shared__ u16 Ps[4 * 32 * 72];      // per-wave [32 q][72 kv]; stages Q (128x72)

  const int tid  = threadIdx.x;
  const int lane = tid & 63;
  const int wid  = tid >> 6;
  const int l16  = lane & 15;
  const int quad = lane >> 4;

  const int idx = blockIdx.x;            // 0..1023
  const int qt  = 15 - (idx >> 6);       // long blocks first
  const int bh  = idx & 63;
  const int bb = bh >> 4, hh = bh & 15;
  const int qbase = qt * 128;

  const u16* Qh = Q  + (size_t)bh * (SEQ * DH);
  const u16* Kh = K  + (size_t)bh * (SEQ * DH);
  const u16* Vh = VT + (size_t)bh * (DH * SEQ);

  // ---- stage Q via Ps (128 rows x 72 stride), pull B-operand frags ----
#pragma unroll
  for (int i = 0; i < 4; i++) {
    const int ch = i * 256 + tid;
    const int r = ch >> 3, c = ch & 7;
    *(uint4_a*)&Ps[r * 72 + c * 8] = *(const uint4_a*)(Qh + (size_t)(qbase + r) * DH + c * 8);
  }
  __syncthreads();

  u16* Pw = &Ps[wid * 32 * 72];          // wave-private slice (= its Q rows)
  bf16x8 qf[2][2];
#pragma unroll
  for (int ct = 0; ct < 2; ct++)
#pragma unroll
    for (int ks = 0; ks < 2; ks++)
      qf[ct][ks] = *(const bf16x8_a*)&Pw[(ct * 16 + l16) * 72 + ks * 32 + quad * 8];

  bf16x8 ones;                           // all-ones A-frag for lsum-via-MFMA
#pragma unroll
  for (int i = 0; i < 8; i++) ones[i] = (short)0x3F80;

  f32x4 o[4][2];                         // O^T [dt][ct]: row dh=quad*4+r, col q=l16
#pragma unroll
  for (int dt = 0; dt < 4; dt++)
#pragma unroll
    for (int ct = 0; ct < 2; ct++) o[dt][ct] = (f32x4){0.f, 0.f, 0.f, 0.f};

  f32x4 lacc[2] = {(f32x4){0.f,0.f,0.f,0.f}, (f32x4){0.f,0.f,0.f,0.f}};
  float mold[2] = {-1e30f, -1e30f};

  const int jmax = 2 * qt + 1;           // kv tiles 0..jmax (64 kv each)

  // prefetch j=0 tiles into registers (8KB each: 512 chunks of 16B)
  uint4 gK[2], gV[2];
#pragma unroll
  for (int i = 0; i < 2; i++) {
    const int ch = i * 256 + tid;
    gK[i] = *(const uint4_a*)(Kh + (size_t)(ch >> 3) * DH + (ch & 7) * 8);
    gV[i] = *(const uint4_a*)(Vh + (size_t)(ch >> 3) * SEQ + (ch & 7) * 8);
  }

  for (int j = 0; j <= jmax; j++) {
    __syncthreads();                     // prior Ks/VTs reads done (all waves)
#pragma unroll
    for (int i = 0; i < 2; i++) {
      const int ch = i * 256 + tid;
      *(uint4_a*)&Ks[(ch >> 3) * 72 + (ch & 7) * 8]  = gK[i];
      *(uint4_a*)&VTs[(ch >> 3) * 72 + (ch & 7) * 8] = gV[i];
    }
    __syncthreads();                     // staging visible

    if (j < jmax) {                      // prefetch j+1; in flight across PV
      const int kb2 = (j + 1) * 64;
#pragma unroll
      for (int i = 0; i < 2; i++) {
        const int ch = i * 256 + tid;
        gK[i] = *(const uint4_a*)(Kh + (size_t)(kb2 + (ch >> 3)) * DH + (ch & 7) * 8);
        gV[i] = *(const uint4_a*)(Vh + (size_t)(ch >> 3) * SEQ + kb2 + (ch & 7) * 8);
      }
    }

    // S^T = K Q^T: rows kv (4x16), cols q (2x16/wave)
    f32x4 s[4][2];
#pragma unroll
    for (int rt = 0; rt < 4; rt++) {
      bf16x8 ka0 = *(const bf16x8_a*)&Ks[(rt * 16 + l16) * 72 + 0 + quad * 8];
      bf16x8 ka1 = *(const bf16x8_a*)&Ks[(rt * 16 + l16) * 72 + 32 + quad * 8];
#pragma unroll
      for (int ct = 0; ct < 2; ct++) {
        f32x4 c = (f32x4){0.f, 0.f, 0.f, 0.f};
        c = MFMA_BF16(ka0, qf[ct][0], c);
        c = MFMA_BF16(ka1, qf[ct][1], c);
        s[rt][ct] = c;
      }
    }

    if (j >= (qt << 1)) {                // diagonal-straddling tiles (last 2)
      const int kvb = j * 64;
#pragma unroll
      for (int rt = 0; rt < 4; rt++)
#pragma unroll
        for (int ct = 0; ct < 2; ct++) {
          const int ql = qbase + wid * 32 + ct * 16 + l16;
#pragma unroll
          for (int r = 0; r < 4; r++) {
            const int kvg = kvb + rt * 16 + quad * 4 + r;
            if (kvg > ql) s[rt][ct][r] = -1e30f;
          }
        }
    }

    // online softmax, shuffle-free common path.
#pragma unroll
    for (int ct = 0; ct < 2; ct++) {
      // per-lane max of own 16 values (in-reg tree; NO cross-lane)
      float m0_ = fmaxf(fmaxf(s[0][ct][0], s[0][ct][1]), fmaxf(s[0][ct][2], s[0][ct][3]));
      float m1_ = fmaxf(fmaxf(s[1][ct][0], s[1][ct][1]), fmaxf(s[1][ct][2], s[1][ct][3]));
      float m2_ = fmaxf(fmaxf(s[2][ct][0], s[2][ct][1]), fmaxf(s[2][ct][2], s[2][ct][3]));
      float m3_ = fmaxf(fmaxf(s[3][ct][0], s[3][ct][1]), fmaxf(s[3][ct][2], s[3][ct][3]));
      const float mloc = fmaxf(fmaxf(m0_, m1_), fmaxf(m2_, m3_));

      // T13 defer: rescale only when some lane's max grew by > 8 (rare).
      if (!__all(mloc - mold[ct] <= 8.0f)) {
        float mt = fmaxf(mloc, __shfl_xor(mloc, 16));
        mt = fmaxf(mt, __shfl_xor(mt, 32));
        const float mnew = fmaxf(mold[ct], mt);
        const float a = __builtin_amdgcn_exp2f((mold[ct] - mnew) * L2E);
        mold[ct] = mnew;
#pragma unroll
        for (int dt = 0; dt < 4; dt++)
#pragma unroll
          for (int r = 0; r < 4; r++) o[dt][ct][r] *= a;
#pragma unroll
        for (int r = 0; r < 4; r++) lacc[ct][r] *= a;
      }
      const float mref = mold[ct];

#pragma unroll
      for (int rt = 0; rt < 4; rt++)
#pragma unroll
        for (int r = 0; r < 4; r++)
          s[rt][ct][r] = __builtin_amdgcn_exp2f((s[rt][ct][r] - mref) * L2E);
      // NOTE: row-sum of P is NOT computed here -- it comes out of the
      // ones-MFMA in the PV phase (matrix pipe, off the critical path).
    }

    // P^T -> wave-private Ps slice: per (rt,ct) 4 consecutive kv -> uint2
#pragma unroll
    for (int rt = 0; rt < 4; rt++) {
#pragma unroll
      for (int ct = 0; ct < 2; ct++) {
        uint2 pk;
        pk.x = pack_bf2(s[rt][ct][0], s[rt][ct][1]);
        pk.y = pack_bf2(s[rt][ct][2], s[rt][ct][3]);
        *(uint2_a*)&Pw[(ct * 16 + l16) * 72 + rt * 16 + quad * 4] = pk;
      }
    }
    // Ps slice is wave-private: same-wave write->read order only (no barrier)
    asm volatile("s_waitcnt lgkmcnt(0)" ::: "memory");

    // O^T += V^T P^T; lacc += 1^T P^T (row-sum on the matrix pipe)
#pragma unroll
    for (int ks2 = 0; ks2 < 2; ks2++) {
      bf16x8 vt[4], pb[2];
#pragma unroll
      for (int dt = 0; dt < 4; dt++)
        vt[dt] = *(const bf16x8_a*)&VTs[(dt * 16 + l16) * 72 + ks2 * 32 + quad * 8];
#pragma unroll
      for (int ct = 0; ct < 2; ct++)
        pb[ct] = *(const bf16x8_a*)&Pw[(ct * 16 + l16) * 72 + ks2 * 32 + quad * 8];
#pragma unroll
      for (int dt = 0; dt < 4; dt++)
#pragma unroll
        for (int ct = 0; ct < 2; ct++)
          o[dt][ct] = MFMA_BF16(vt[dt], pb[ct], o[dt][ct]);
#pragma unroll
      for (int ct = 0; ct < 2; ct++)
        lacc[ct] = MFMA_BF16(ones, pb[ct], lacc[ct]);
    }
  }

  // epilogue: O^T row dh = dt*16+quad*4+r, col q = l16 -> float4 stores.
  // lacc rows are all identical (= sum over kv of P for col q) -> [0].
#pragma unroll
  for (int ct = 0; ct < 2; ct++) {
    const float inv = 1.0f / lacc[ct][0];
    const int qg = qbase + wid * 32 + ct * 16 + l16;
    float* orow = O + (size_t)((size_t)bb * SEQ + qg) * DMODEL + hh * 64;
#pragma unroll
    for (int dt = 0; dt < 4; dt++) {
      float4 v4;
      v4.x = o[dt][ct][0] * inv;  v4.y = o[dt][ct][1] * inv;
      v4.z = o[dt][ct][2] * inv;  v4.w = o[dt][ct][3] * inv;
      *(float4_a*)&orow[dt * 16 + quad * 4] = v4;
    }
  }
}

// Distinctive-paint sentinel (host-decided, graph-safe)
__global__ void paintf(float* out, int n, float v) {
  int i = blockIdx.x * 256 + threadIdx.x;
  if (i < n) out[i] = v;
}

extern "C" void kernel_launch(void* const* d_in, const int* in_sizes, int n_in,
                              void* d_out, int out_size, void* d_ws, size_t ws_size,
                              hipStream_t stream) {
  float* out = (float*)d_out;

  const size_t elems  = (size_t)4 * SEQ * DMODEL;   // 8,388,608 per tensor
  const size_t welems = (size_t)DMODEL * DMODEL;    // 1,048,576 per W
  const size_t need_old = 3 * elems * sizeof(u16);
  const size_t need_new = (4 * elems + 3 * welems) * sizeof(u16);  // ~70 MB

  if (ws_size < need_old) {
    paintf<<<(out_size + 255) / 256, 256, 0, stream>>>(out, out_size, 3.0e38f);
    return;
  }

  const float* x  = (const float*)d_in[0];
  // d_in[1] = mask (causal, unused — structure is known)
  const float* Wq = (const float*)d_in[2];
  const float* bq = (const float*)d_in[3];
  const float* Wk = (const float*)d_in[4];
  const float* bk = (const float*)d_in[5];
  const float* Wv = (const float*)d_in[6];
  const float* bv = (const float*)d_in[7];

  u16* q = (u16*)d_ws;
  u16* k = q + elems;
  u16* v = k + elems;   // holds V^T [B,H,DH,S]

  if (ws_size >= need_new) {
    u16* xb  = v + elems;
    u16* wqb = xb + elems;
    u16* wkb = wqb + welems;
    u16* wvb = wkb + welems;
    cvt_x_bf16<<<2048, 256, 0, stream>>>(x, xb, (int)(elems / 8));
    cvt_w_bf16<<<dim3(512, 3), 256, 0, stream>>>(Wq, Wk, Wv, wqb, wkb, wvb);
    qkv_gemm_bf<<<dim3(64, 4, 3), 256, 0, stream>>>(xb, wqb, wkb, wvb, bq, bk, bv, q, k, v);
  } else {
    qkv_gemm<<<dim3(64, 8, 3), 256, 0, stream>>>(x, Wq, Wk, Wv, bq, bk, bv, q, k, v);
  }

  flash_attn<<<1024, 256, 0, stream>>>(q, k, v, out);
}

// Round 6
// 255.630 us; speedup vs baseline: 1.1707x; 1.0586x over previous
//
#include <hip/hip_runtime.h>
#include <hip/hip_bf16.h>
#include <stdint.h>

typedef unsigned short u16;
typedef unsigned int   u32;
typedef short bf16x8 __attribute__((ext_vector_type(8)));
typedef float f32x4  __attribute__((ext_vector_type(4)));

// may_alias views for type-punned LDS/global accesses (TBAA-safe)
typedef bf16x8 __attribute__((__may_alias__)) bf16x8_a;
typedef uint4  __attribute__((__may_alias__)) uint4_a;
typedef uint2  __attribute__((__may_alias__)) uint2_a;
typedef float4 __attribute__((__may_alias__)) float4_a;

#define MFMA_BF16(a,b,c) __builtin_amdgcn_mfma_f32_16x16x32_bf16((a),(b),(c),0,0,0)
#define L2E 1.44269504088896340736f

// B=4, S=2048, D=1024, H=16, DH=64
#define SEQ 2048
#define DMODEL 1024
#define NH 16
#define DH 64

__device__ __forceinline__ u32 pack_bf2(float a, float b) {
  union { __hip_bfloat162 h; u32 u; } c;
  c.h = __float22bfloat162_rn(make_float2(a, b));   // v_cvt_pk path on gfx950
  return c.u;
}

__device__ __forceinline__ u16 f2bf(float f) {
  u32 u = __builtin_bit_cast(u32, f);
  u += 0x7FFFu + ((u >> 16) & 1u);
  return (u16)(u >> 16);
}

// global -> LDS direct DMA, 16B/lane. LDS dest is wave-uniform base + lane*16.
__device__ __forceinline__ void gl_lds16(const u16* g, u16* l) {
  __builtin_amdgcn_global_load_lds(
      (const __attribute__((address_space(1))) void*)g,
      (__attribute__((address_space(3))) void*)l, 16, 0, 0);
}

// ---------------------------------------------------------------------------
// One-time f32 -> bf16 convert, FUSED (x + Wq/Wk/Wv in one launch).
// chunks of 8 floats; x = 1<<20 chunks, each W = 1<<17 chunks. grid 5632x256.
// ---------------------------------------------------------------------------
__global__ __launch_bounds__(256) void cvt_all_bf16(
    const float* __restrict__ x,
    const float* __restrict__ wq, const float* __restrict__ wk, const float* __restrict__ wv,
    u16* __restrict__ xb, u16* __restrict__ oq, u16* __restrict__ ok, u16* __restrict__ ov)
{
  const int c = blockIdx.x * 256 + threadIdx.x;
  const float* s; u16* d; int off;
  if (c < (1 << 20)) { s = x; d = xb; off = c; }
  else {
    const int c2 = c - (1 << 20);
    const int w = c2 >> 17;
    off = c2 & ((1 << 17) - 1);
    s = (w == 0) ? wq : (w == 1) ? wk : wv;
    d = (w == 0) ? oq : (w == 1) ? ok : ov;
  }
  const float4_a* p = (const float4_a*)(s + (size_t)off * 8);
  float4 a = p[0], b = p[1];
  uint4 o;
  o.x = pack_bf2(a.x, a.y); o.y = pack_bf2(a.z, a.w);
  o.z = pack_bf2(b.x, b.y); o.w = pack_bf2(b.z, b.w);
  *(uint4_a*)(d + (size_t)off * 8) = o;
}

// ---------------------------------------------------------------------------
// QKV projection, bf16 in -> bf16 out (FROZEN from R5). 128x128 tile, BK=32,
// dbuf LDS, counted vmcnt(4), raw barriers; grid (64,4,3) = 768 blocks = 3/CU,
// 2 sequential n-subtiles per block.
// ---------------------------------------------------------------------------
__global__ __launch_bounds__(256, 3) void qkv_gemm_bf(
    const u16* __restrict__ Xb,
    const u16* __restrict__ Wqb, const u16* __restrict__ Wkb, const u16* __restrict__ Wvb,
    const float* __restrict__ Bq, const float* __restrict__ Bk, const float* __restrict__ Bv,
    u16* __restrict__ Qo, u16* __restrict__ Ko, u16* __restrict__ Vo)
{
  __shared__ u16 As[2][128 * 32];   // [buf][m][k] bf16, row = 64B
  __shared__ u16 Bs[2][128 * 32];   // [buf][n][k] bf16

  const int tid  = threadIdx.x;
  const int lane = tid & 63;
  const int wid  = tid >> 6;
  const int l16  = lane & 15;
  const int quad = lane >> 4;
  const int wm   = (wid >> 1) * 64;
  const int wn   = (wid & 1) * 64;

  const int m0 = blockIdx.x * 128;
  const int pj = blockIdx.z;

  const u16*   Wb   = (pj == 0) ? Wqb : (pj == 1) ? Wkb : Wvb;
  const float* Bias = (pj == 0) ? Bq : (pj == 1) ? Bk : Bv;
  u16*         Out  = (pj == 0) ? Qo : (pj == 1) ? Ko : Vo;
  const float scale = (pj == 0) ? 0.125f : 1.0f;

  const int lr = lane >> 2;          // row within a 16-row band (4 lanes/row)
  const int lc = (lane & 3) * 8;     // bf16 col offset (8 bf16 = 16B per lane)

  const u16* Arow = Xb + (size_t)m0 * DMODEL;
  const int NT = DMODEL / 32;        // 32 K-steps

  for (int nsub = 0; nsub < 2; ++nsub) {
    const int n0 = blockIdx.y * 256 + nsub * 128;
    const u16* Brow = Wb + (size_t)n0 * DMODEL;

    f32x4 acc[4][4];
#pragma unroll
    for (int i = 0; i < 4; i++)
#pragma unroll
      for (int j = 0; j < 4; j++) acc[i][j] = (f32x4){0.f, 0.f, 0.f, 0.f};

    // prologue: stage tiles 0,1 into buf 0,1 (8 gl_lds outstanding per wave)
#pragma unroll
    for (int c = 0; c < 2; c++) {
      const int band = c * 64 + wid * 16;
      gl_lds16(Arow + (size_t)(band + lr) * DMODEL + 0 + lc, &As[0][band * 32]);
      gl_lds16(Brow + (size_t)(band + lr) * DMODEL + 0 + lc, &Bs[0][band * 32]);
    }
#pragma unroll
    for (int c = 0; c < 2; c++) {
      const int band = c * 64 + wid * 16;
      gl_lds16(Arow + (size_t)(band + lr) * DMODEL + 32 + lc, &As[1][band * 32]);
      gl_lds16(Brow + (size_t)(band + lr) * DMODEL + 32 + lc, &Bs[1][band * 32]);
    }

    for (int t = 0; t < NT; ++t) {
      const int cur = t & 1;
      // wait for buf[cur]'s 4 loads (oldest); leave newest 4 in flight.
      if (t < NT - 1) asm volatile("s_waitcnt vmcnt(4)" ::: "memory");
      else            asm volatile("s_waitcnt vmcnt(0)" ::: "memory");
      __builtin_amdgcn_s_barrier();          // all waves' buf[cur] landed

      bf16x8 a[4], b[4];
#pragma unroll
      for (int mt = 0; mt < 4; mt++)
        a[mt] = *(const bf16x8_a*)&As[cur][(wm + mt * 16 + l16) * 32 + quad * 8];
#pragma unroll
      for (int nt = 0; nt < 4; nt++)
        b[nt] = *(const bf16x8_a*)&Bs[cur][(wn + nt * 16 + l16) * 32 + quad * 8];

      asm volatile("s_waitcnt lgkmcnt(0)" ::: "memory");  // frags in regs
      __builtin_amdgcn_sched_barrier(0);                  // rule #18
      __builtin_amdgcn_s_barrier();          // all waves done reading buf[cur]

      if (t + 2 < NT) {                      // overwrite buf[cur] with tile t+2
        const int kt2 = (t + 2) * 32;
#pragma unroll
        for (int c = 0; c < 2; c++) {
          const int band = c * 64 + wid * 16;
          gl_lds16(Arow + (size_t)(band + lr) * DMODEL + kt2 + lc, &As[cur][band * 32]);
          gl_lds16(Brow + (size_t)(band + lr) * DMODEL + kt2 + lc, &Bs[cur][band * 32]);
        }
      }

#pragma unroll
      for (int mt = 0; mt < 4; mt++)
#pragma unroll
        for (int nt = 0; nt < 4; nt++)
          acc[mt][nt] = MFMA_BF16(a[mt], b[nt], acc[mt][nt]);
    }

    // Epilogue. C layout: col n = l16(+), row m = quad*4+r(+).
    if (pj == 2) {
      // V stored TRANSPOSED [B,H,DH,S]: per lane 4 consecutive s -> uint2 pack
#pragma unroll
      for (int mt = 0; mt < 4; mt++) {
#pragma unroll
        for (int nt = 0; nt < 4; nt++) {
          const int n = n0 + wn + nt * 16 + l16;
          const float bias = Bias[n];
          const int h = n >> 6, dh = n & 63;
          const int m = m0 + wm + mt * 16 + quad * 4;
          const int bb = m >> 11, ss = m & 2047;
          uint2 pk;
          pk.x = pack_bf2(acc[mt][nt][0] + bias, acc[mt][nt][1] + bias);
          pk.y = pack_bf2(acc[mt][nt][2] + bias, acc[mt][nt][3] + bias);
          *(uint2_a*)&Out[((size_t)(bb * NH + h) * DH + dh) * SEQ + ss] = pk;
        }
      }
    } else {
#pragma unroll
      for (int mt = 0; mt < 4; mt++) {
#pragma unroll
        for (int nt = 0; nt < 4; nt++) {
          const int n = n0 + wn + nt * 16 + l16;
          const float bias = Bias[n];
          const int h = n >> 6, dh = n & 63;
#pragma unroll
          for (int r = 0; r < 4; r++) {
            const int m = m0 + wm + mt * 16 + quad * 4 + r;
            const int bb = m >> 11, ss = m & 2047;
            Out[((((size_t)bb * NH + h) * SEQ + ss) << 6) + dh] = f2bf((acc[mt][nt][r] + bias) * scale);
          }
        }
      }
    }

    if (nsub == 0) {
      // drain epilogue stores so the next subtile's vmcnt(4) count is clean
      asm volatile("s_waitcnt vmcnt(0)" ::: "memory");
    }
  }
}

// ---------------------------------------------------------------------------
// QKV projection, f32 in -> bf16 ws (FALLBACK path when ws too small).
// ---------------------------------------------------------------------------
__global__ __launch_bounds__(256, 2) void qkv_gemm(
    const float* __restrict__ X,
    const float* __restrict__ Wq, const float* __restrict__ Wk, const float* __restrict__ Wv,
    const float* __restrict__ Bq, const float* __restrict__ Bk, const float* __restrict__ Bv,
    u16* __restrict__ Qo, u16* __restrict__ Ko, u16* __restrict__ Vo)
{
  __shared__ u16 As[128 * 32];
  __shared__ u16 Bs[128 * 32];

  const int tid  = threadIdx.x;
  const int lane = tid & 63;
  const int wid  = tid >> 6;
  const int l16  = lane & 15;
  const int quad = lane >> 4;
  const int wm   = (wid >> 1) * 64;
  const int wn   = (wid & 1) * 64;

  const int m0 = blockIdx.x * 128;
  const int n0 = blockIdx.y * 128;
  const int pj = blockIdx.z;

  const float* W    = (pj == 0) ? Wq : (pj == 1) ? Wk : Wv;
  const float* Bias = (pj == 0) ? Bq : (pj == 1) ? Bk : Bv;
  u16*         Out  = (pj == 0) ? Qo : (pj == 1) ? Ko : Vo;
  const float scale = (pj == 0) ? 0.125f : 1.0f;

  f32x4 acc[4][4];
#pragma unroll
  for (int i = 0; i < 4; i++)
#pragma unroll
    for (int j = 0; j < 4; j++) acc[i][j] = (f32x4){0.f, 0.f, 0.f, 0.f};

  float4 gX[4], gW[4];
#pragma unroll
  for (int i = 0; i < 4; i++) {
    const int ch = i * 256 + tid;
    const int r = ch >> 3, c = ch & 7;
    gX[i] = *(const float4_a*)(X + (size_t)(m0 + r) * DMODEL + c * 4);
    gW[i] = *(const float4_a*)(W + (size_t)(n0 + r) * DMODEL + c * 4);
  }

  for (int kt = 0; kt < DMODEL; kt += 32) {
    __syncthreads();
#pragma unroll
    for (int i = 0; i < 4; i++) {
      const int ch = i * 256 + tid;
      const int r = ch >> 3, c = ch & 7;
      uint2 xp, wp;
      xp.x = pack_bf2(gX[i].x, gX[i].y);  xp.y = pack_bf2(gX[i].z, gX[i].w);
      wp.x = pack_bf2(gW[i].x, gW[i].y);  wp.y = pack_bf2(gW[i].z, gW[i].w);
      *(uint2_a*)&As[r * 32 + c * 4] = xp;
      *(uint2_a*)&Bs[r * 32 + c * 4] = wp;
    }
    __syncthreads();

    if (kt + 32 < DMODEL) {
#pragma unroll
      for (int i = 0; i < 4; i++) {
        const int ch = i * 256 + tid;
        const int r = ch >> 3, c = ch & 7;
        gX[i] = *(const float4_a*)(X + (size_t)(m0 + r) * DMODEL + kt + 32 + c * 4);
        gW[i] = *(const float4_a*)(W + (size_t)(n0 + r) * DMODEL + kt + 32 + c * 4);
      }
    }

    bf16x8 a[4], b[4];
#pragma unroll
    for (int mt = 0; mt < 4; mt++)
      a[mt] = *(const bf16x8_a*)&As[(wm + mt * 16 + l16) * 32 + quad * 8];
#pragma unroll
    for (int nt = 0; nt < 4; nt++)
      b[nt] = *(const bf16x8_a*)&Bs[(wn + nt * 16 + l16) * 32 + quad * 8];
#pragma unroll
    for (int mt = 0; mt < 4; mt++)
#pragma unroll
      for (int nt = 0; nt < 4; nt++)
        acc[mt][nt] = MFMA_BF16(a[mt], b[nt], acc[mt][nt]);
  }

  if (pj == 2) {
#pragma unroll
    for (int mt = 0; mt < 4; mt++) {
#pragma unroll
      for (int nt = 0; nt < 4; nt++) {
        const int n = n0 + wn + nt * 16 + l16;
        const float bias = Bias[n];
        const int h = n >> 6, dh = n & 63;
        const int m = m0 + wm + mt * 16 + quad * 4;
        const int bb = m >> 11, ss = m & 2047;
        uint2 pk;
        pk.x = pack_bf2(acc[mt][nt][0] + bias, acc[mt][nt][1] + bias);
        pk.y = pack_bf2(acc[mt][nt][2] + bias, acc[mt][nt][3] + bias);
        *(uint2_a*)&Out[((size_t)(bb * NH + h) * DH + dh) * SEQ + ss] = pk;
      }
    }
  } else {
#pragma unroll
    for (int mt = 0; mt < 4; mt++) {
#pragma unroll
      for (int nt = 0; nt < 4; nt++) {
        const int n = n0 + wn + nt * 16 + l16;
        const float bias = Bias[n];
        const int h = n >> 6, dh = n & 63;
#pragma unroll
        for (int r = 0; r < 4; r++) {
          const int m = m0 + wm + mt * 16 + quad * 4 + r;
          const int bb = m >> 11, ss = m & 2047;
          Out[((((size_t)bb * NH + h) * SEQ + ss) << 6) + dh] = f2bf((acc[mt][nt][r] + bias) * scale);
        }
      }
    }
  }
}

// ---------------------------------------------------------------------------
// Causal flash attention. THIS ROUND: K/V LDS DOUBLE-BUFFER -> ONE barrier
// per iteration (staging writes overlap softmax; was bar->write->bar serial).
// Stride-64 K/V rows with G4 XOR swizzle (colElem ^= (row&7)<<3) on BOTH
// write and read sides -> LDS 50KB -> 3 blocks/CU. Shuffle-free softmax +
// lsum-via-ones-MFMA + T13 defer (R5). 2-tile-deep register prefetch.
// Q,K [B*H][S][DH]; V TRANSPOSED [B*H][DH][S]. Q pre-scaled 1/8.
// ---------------------------------------------------------------------------
__global__ __launch_bounds__(256, 3) void flash_attn(
    const u16* __restrict__ Q, const u16* __restrict__ K, const u16* __restrict__ VT,
    float* __restrict__ O)
{
  __shared__ u16 Ks[2][64 * 64];       // [buf][kv][64 swz]  8 KB each
  __shared__ u16 VTs[2][64 * 64];      // [buf][dh][64 swz]  8 KB each
  __shared__ u16 Ps[4 * 32 * 72];      // per-wave [32 q][72 kv]; stages Q (128x72)

  const int tid  = threadIdx.x;
  const int lane = tid & 63;
  const int wid  = tid >> 6;
  const int l16  = lane & 15;
  const int quad = lane >> 4;

  const int idx = blockIdx.x;            // 0..1023
  const int qt  = 15 - (idx >> 6);       // long blocks first
  const int bh  = idx & 63;
  const int bb = bh >> 4, hh = bh & 15;
  const int qbase = qt * 128;

  const u16* Qh = Q  + (size_t)bh * (SEQ * DH);
  const u16* Kh = K  + (size_t)bh * (SEQ * DH);
  const u16* Vh = VT + (size_t)bh * (DH * SEQ);

  // ---- stage Q via Ps (128 rows x 72 stride), pull B-operand frags ----
#pragma unroll
  for (int i = 0; i < 4; i++) {
    const int ch = i * 256 + tid;
    const int r = ch >> 3, c = ch & 7;
    *(uint4_a*)&Ps[r * 72 + c * 8] = *(const uint4_a*)(Qh + (size_t)(qbase + r) * DH + c * 8);
  }
  __syncthreads();

  u16* Pw = &Ps[wid * 32 * 72];          // wave-private slice (= its Q rows)
  bf16x8 qf[2][2];
#pragma unroll
  for (int ct = 0; ct < 2; ct++)
#pragma unroll
    for (int ks = 0; ks < 2; ks++)
      qf[ct][ks] = *(const bf16x8_a*)&Pw[(ct * 16 + l16) * 72 + ks * 32 + quad * 8];

  bf16x8 ones;                           // all-ones A-frag for lsum-via-MFMA
#pragma unroll
  for (int i = 0; i < 8; i++) ones[i] = (short)0x3F80;

  f32x4 o[4][2];                         // O^T [dt][ct]: row dh=quad*4+r, col q=l16
#pragma unroll
  for (int dt = 0; dt < 4; dt++)
#pragma unroll
    for (int ct = 0; ct < 2; ct++) o[dt][ct] = (f32x4){0.f, 0.f, 0.f, 0.f};

  f32x4 lacc[2] = {(f32x4){0.f,0.f,0.f,0.f}, (f32x4){0.f,0.f,0.f,0.f}};
  float mold[2] = {-1e30f, -1e30f};

  const int jmax = 2 * qt + 1;           // kv tiles 0..jmax (64 kv each); >=1
  const int swz  = (l16 & 7) << 3;       // read-side XOR (elements)

  // prefetch tile 0 into registers (8KB: 512 chunks of 16B)
  uint4 gK[2], gV[2];
#pragma unroll
  for (int i = 0; i < 2; i++) {
    const int ch = i * 256 + tid;
    gK[i] = *(const uint4_a*)(Kh + (size_t)(ch >> 3) * DH + (ch & 7) * 8);
    gV[i] = *(const uint4_a*)(Vh + (size_t)(ch >> 3) * SEQ + (ch & 7) * 8);
  }
  // wait & write buf0 (swizzled)
  asm volatile("s_waitcnt vmcnt(0)" ::: "memory");
#pragma unroll
  for (int i = 0; i < 2; i++) {
    const int ch = i * 256 + tid;
    const int row = ch >> 3, col = (ch & 7) * 8;
    *(uint4_a*)&Ks[0][row * 64 + (col ^ ((row & 7) << 3))]  = gK[i];
    *(uint4_a*)&VTs[0][row * 64 + (col ^ ((row & 7) << 3))] = gV[i];
  }
  // prefetch tile 1
#pragma unroll
  for (int i = 0; i < 2; i++) {
    const int ch = i * 256 + tid;
    gK[i] = *(const uint4_a*)(Kh + (size_t)(64 + (ch >> 3)) * DH + (ch & 7) * 8);
    gV[i] = *(const uint4_a*)(Vh + (size_t)(ch >> 3) * SEQ + 64 + (ch & 7) * 8);
  }
  asm volatile("s_waitcnt lgkmcnt(0)" ::: "memory");
  __builtin_amdgcn_sched_barrier(0);
  __builtin_amdgcn_s_barrier();          // buf0 visible to all waves

  for (int j = 0; j <= jmax; j++) {
    const int cur = j & 1;
    const u16* Kc = Ks[cur];
    const u16* Vc = VTs[cur];

    // S^T = K Q^T: rows kv (4x16), cols q (2x16/wave)
    f32x4 s[4][2];
#pragma unroll
    for (int rt = 0; rt < 4; rt++) {
      bf16x8 ka0 = *(const bf16x8_a*)&Kc[(rt * 16 + l16) * 64 + ((0  + quad * 8) ^ swz)];
      bf16x8 ka1 = *(const bf16x8_a*)&Kc[(rt * 16 + l16) * 64 + ((32 + quad * 8) ^ swz)];
#pragma unroll
      for (int ct = 0; ct < 2; ct++) {
        f32x4 c = (f32x4){0.f, 0.f, 0.f, 0.f};
        c = MFMA_BF16(ka0, qf[ct][0], c);
        c = MFMA_BF16(ka1, qf[ct][1], c);
        s[rt][ct] = c;
      }
    }

    if (j >= (qt << 1)) {                // diagonal-straddling tiles (last 2)
      const int kvb = j * 64;
#pragma unroll
      for (int rt = 0; rt < 4; rt++)
#pragma unroll
        for (int ct = 0; ct < 2; ct++) {
          const int ql = qbase + wid * 32 + ct * 16 + l16;
#pragma unroll
          for (int r = 0; r < 4; r++) {
            const int kvg = kvb + rt * 16 + quad * 4 + r;
            if (kvg > ql) s[rt][ct][r] = -1e30f;
          }
        }
    }

    // ---- stage tile j+1 into buf[cur^1] (overlaps softmax; 1 barrier/iter)
    if (j < jmax) {
      asm volatile("s_waitcnt vmcnt(0)" ::: "memory");   // gK/gV(j+1) landed
      const int nxt = cur ^ 1;
#pragma unroll
      for (int i = 0; i < 2; i++) {
        const int ch = i * 256 + tid;
        const int row = ch >> 3, col = (ch & 7) * 8;
        *(uint4_a*)&Ks[nxt][row * 64 + (col ^ ((row & 7) << 3))]  = gK[i];
        *(uint4_a*)&VTs[nxt][row * 64 + (col ^ ((row & 7) << 3))] = gV[i];
      }
      if (j + 1 < jmax) {                // prefetch tile j+2
        const int kb2 = (j + 2) * 64;
#pragma unroll
        for (int i = 0; i < 2; i++) {
          const int ch = i * 256 + tid;
          gK[i] = *(const uint4_a*)(Kh + (size_t)(kb2 + (ch >> 3)) * DH + (ch & 7) * 8);
          gV[i] = *(const uint4_a*)(Vh + (size_t)(ch >> 3) * SEQ + kb2 + (ch & 7) * 8);
        }
      }
    }

    // online softmax, shuffle-free common path (R5).
#pragma unroll
    for (int ct = 0; ct < 2; ct++) {
      float m0_ = fmaxf(fmaxf(s[0][ct][0], s[0][ct][1]), fmaxf(s[0][ct][2], s[0][ct][3]));
      float m1_ = fmaxf(fmaxf(s[1][ct][0], s[1][ct][1]), fmaxf(s[1][ct][2], s[1][ct][3]));
      float m2_ = fmaxf(fmaxf(s[2][ct][0], s[2][ct][1]), fmaxf(s[2][ct][2], s[2][ct][3]));
      float m3_ = fmaxf(fmaxf(s[3][ct][0], s[3][ct][1]), fmaxf(s[3][ct][2], s[3][ct][3]));
      const float mloc = fmaxf(fmaxf(m0_, m1_), fmaxf(m2_, m3_));

      // T13 defer: rescale only when some lane's max grew by > 8 (rare).
      if (!__all(mloc - mold[ct] <= 8.0f)) {
        float mt = fmaxf(mloc, __shfl_xor(mloc, 16));
        mt = fmaxf(mt, __shfl_xor(mt, 32));
        const float mnew = fmaxf(mold[ct], mt);
        const float a = __builtin_amdgcn_exp2f((mold[ct] - mnew) * L2E);
        mold[ct] = mnew;
#pragma unroll
        for (int dt = 0; dt < 4; dt++)
#pragma unroll
          for (int r = 0; r < 4; r++) o[dt][ct][r] *= a;
#pragma unroll
        for (int r = 0; r < 4; r++) lacc[ct][r] *= a;
      }
      const float mref = mold[ct];

#pragma unroll
      for (int rt = 0; rt < 4; rt++)
#pragma unroll
        for (int r = 0; r < 4; r++)
          s[rt][ct][r] = __builtin_amdgcn_exp2f((s[rt][ct][r] - mref) * L2E);
      // row-sum of P comes out of the ones-MFMA in PV (matrix pipe).
    }

    // P^T -> wave-private Ps slice: per (rt,ct) 4 consecutive kv -> uint2
#pragma unroll
    for (int rt = 0; rt < 4; rt++) {
#pragma unroll
      for (int ct = 0; ct < 2; ct++) {
        uint2 pk;
        pk.x = pack_bf2(s[rt][ct][0], s[rt][ct][1]);
        pk.y = pack_bf2(s[rt][ct][2], s[rt][ct][3]);
        *(uint2_a*)&Pw[(ct * 16 + l16) * 72 + rt * 16 + quad * 4] = pk;
      }
    }
    // drains P writes AND staging writes (wave-local ordering)
    asm volatile("s_waitcnt lgkmcnt(0)" ::: "memory");
    __builtin_amdgcn_sched_barrier(0);   // rule #18

    // O^T += V^T P^T; lacc += 1^T P^T (row-sum on the matrix pipe)
#pragma unroll
    for (int ks2 = 0; ks2 < 2; ks2++) {
      bf16x8 vt[4], pb[2];
#pragma unroll
      for (int dt = 0; dt < 4; dt++)
        vt[dt] = *(const bf16x8_a*)&Vc[(dt * 16 + l16) * 64 + ((ks2 * 32 + quad * 8) ^ swz)];
#pragma unroll
      for (int ct = 0; ct < 2; ct++)
        pb[ct] = *(const bf16x8_a*)&Pw[(ct * 16 + l16) * 72 + ks2 * 32 + quad * 8];
#pragma unroll
      for (int dt = 0; dt < 4; dt++)
#pragma unroll
        for (int ct = 0; ct < 2; ct++)
          o[dt][ct] = MFMA_BF16(vt[dt], pb[ct], o[dt][ct]);
#pragma unroll
      for (int ct = 0; ct < 2; ct++)
        lacc[ct] = MFMA_BF16(ones, pb[ct], lacc[ct]);
    }

    __builtin_amdgcn_sched_barrier(0);
    __builtin_amdgcn_s_barrier();        // end of iter: buf[cur^1] visible,
                                         // buf[cur] reads retired (in regs)
  }

  // epilogue: O^T row dh = dt*16+quad*4+r, col q = l16 -> float4 stores.
  // lacc rows are all identical (= sum over kv of P for col q) -> [0].
#pragma unroll
  for (int ct = 0; ct < 2; ct++) {
    const float inv = 1.0f / lacc[ct][0];
    const int qg = qbase + wid * 32 + ct * 16 + l16;
    float* orow = O + (size_t)((size_t)bb * SEQ + qg) * DMODEL + hh * 64;
#pragma unroll
    for (int dt = 0; dt < 4; dt++) {
      float4 v4;
      v4.x = o[dt][ct][0] * inv;  v4.y = o[dt][ct][1] * inv;
      v4.z = o[dt][ct][2] * inv;  v4.w = o[dt][ct][3] * inv;
      *(float4_a*)&orow[dt * 16 + quad * 4] = v4;
    }
  }
}

// Distinctive-paint sentinel (host-decided, graph-safe)
__global__ void paintf(float* out, int n, float v) {
  int i = blockIdx.x * 256 + threadIdx.x;
  if (i < n) out[i] = v;
}

extern "C" void kernel_launch(void* const* d_in, const int* in_sizes, int n_in,
                              void* d_out, int out_size, void* d_ws, size_t ws_size,
                              hipStream_t stream) {
  float* out = (float*)d_out;

  const size_t elems  = (size_t)4 * SEQ * DMODEL;   // 8,388,608 per tensor
  const size_t welems = (size_t)DMODEL * DMODEL;    // 1,048,576 per W
  const size_t need_old = 3 * elems * sizeof(u16);
  const size_t need_new = (4 * elems + 3 * welems) * sizeof(u16);  // ~70 MB

  if (ws_size < need_old) {
    paintf<<<(out_size + 255) / 256, 256, 0, stream>>>(out, out_size, 3.0e38f);
    return;
  }

  const float* x  = (const float*)d_in[0];
  // d_in[1] = mask (causal, unused — structure is known)
  const float* Wq = (const float*)d_in[2];
  const float* bq = (const float*)d_in[3];
  const float* Wk = (const float*)d_in[4];
  const float* bk = (const float*)d_in[5];
  const float* Wv = (const float*)d_in[6];
  const float* bv = (const float*)d_in[7];

  u16* q = (u16*)d_ws;
  u16* k = q + elems;
  u16* v = k + elems;   // holds V^T [B,H,DH,S]

  if (ws_size >= need_new) {
    u16* xb  = v + elems;
    u16* wqb = xb + elems;
    u16* wkb = wqb + welems;
    u16* wvb = wkb + welems;
    cvt_all_bf16<<<5632, 256, 0, stream>>>(x, Wq, Wk, Wv, xb, wqb, wkb, wvb);
    qkv_gemm_bf<<<dim3(64, 4, 3), 256, 0, stream>>>(xb, wqb, wkb, wvb, bq, bk, bv, q, k, v);
  } else {
    qkv_gemm<<<dim3(64, 8, 3), 256, 0, stream>>>(x, Wq, Wk, Wv, bq, bk, bv, q, k, v);
  }

  flash_attn<<<1024, 256, 0, stream>>>(q, k, v, out);
}